// Round 4
// baseline (747.246 us; speedup 1.0000x reference)
//
#include <hip/hip_runtime.h>
#include <hip/hip_bf16.h>

// 3-layer GCN. Round 4: bucketed CSR build.
//   bincount (LDS histogram, 128-node buckets) -> bucket_scan (1 block)
//   -> bin_scatter (packed src|dlocal into bucket-major staging)
//   -> bucket_place (per-bucket LDS scan: row_ptr, dinv, csr_src)
// GEMMs: bf16 MFMA 16x16x32. Aggregation: CSR wave-per-node gather, bf16 H.
// Requires N <= 131072 (bucket count <= 1024) and N < 2^25 for packing.

#define FEAT 128
#define OUTF 64
#define BSH 7                 // 128 nodes per bucket
#define BNODES (1 << BSH)

typedef __attribute__((ext_vector_type(8))) short short8;
typedef __attribute__((ext_vector_type(4))) float f32x4;

__device__ __forceinline__ unsigned short bf16_rn(float f) {
    unsigned int u = __float_as_uint(f);
    u += 0x7FFFu + ((u >> 16) & 1u);   // round-to-nearest-even
    return (unsigned short)(u >> 16);
}
__device__ __forceinline__ float bf16_lo(unsigned int u) { return __uint_as_float(u << 16); }
__device__ __forceinline__ float bf16_hi(unsigned int u) { return __uint_as_float(u & 0xFFFF0000u); }

// ---- k1: per-bucket edge counts (LDS histogram; NB <= 1024) ----
__global__ __launch_bounds__(256) void bincount_kernel(
        const int* __restrict__ dst, int* __restrict__ bcnt, int E, int NB) {
    __shared__ int h[1024];
    int t = threadIdx.x;
    for (int i = t; i < NB; i += 256) h[i] = 0;
    __syncthreads();
    int stride = gridDim.x * 256;
    for (int e = blockIdx.x * 256 + t; e < E; e += stride)
        atomicAdd(&h[dst[e] >> BSH], 1);
    __syncthreads();
    for (int i = t; i < NB; i += 256)
        if (h[i]) atomicAdd(&bcnt[i], h[i]);
}

// ---- k2: exclusive scan of bcnt[NB] -> bbase[NB+1]; zero bcur ----
__global__ __launch_bounds__(256) void bucket_scan_kernel(
        const int* __restrict__ bcnt, int* __restrict__ bbase,
        int* __restrict__ bcur, int NB, int E) {
    int t = threadIdx.x;
    int base = t * 4;
    int v[4];
    #pragma unroll
    for (int i = 0; i < 4; ++i) v[i] = (base + i < NB) ? bcnt[base + i] : 0;
    int local = v[0] + v[1] + v[2] + v[3];
    int lane = t & 63, wv = t >> 6;
    int x = local;
    #pragma unroll
    for (int o = 1; o < 64; o <<= 1) {
        int y = __shfl_up(x, o);
        if (lane >= o) x += y;
    }
    __shared__ int wsum[4];
    if (lane == 63) wsum[wv] = x;
    __syncthreads();
    int woff = 0;
    for (int i = 0; i < wv; ++i) woff += wsum[i];
    int run = woff + x - local;
    #pragma unroll
    for (int i = 0; i < 4; ++i) {
        if (base + i < NB) bbase[base + i] = run;
        run += v[i];
    }
    for (int i = t; i < NB; i += 256) bcur[i] = 0;
    if (t == 0) bbase[NB] = E;
}

// ---- k3: scatter packed (src | dlocal<<25) into bucket-major staging ----
__global__ __launch_bounds__(256) void bin_scatter_kernel(
        const int* __restrict__ src, const int* __restrict__ dst,
        const int* __restrict__ bbase, int* __restrict__ bcur,
        unsigned int* __restrict__ staged, int E) {
    int e = blockIdx.x * 256 + threadIdx.x;
    if (e < E) {
        int s = src[e], d = dst[e];
        int b = d >> BSH, dl = d & (BNODES - 1);
        int pos = bbase[b] + atomicAdd(&bcur[b], 1);
        staged[pos] = (unsigned int)s | ((unsigned int)dl << 25);
    }
}

// ---- k4: per-bucket finalize: row_ptr, dinv, csr_src ----
__global__ __launch_bounds__(256) void bucket_place_kernel(
        const unsigned int* __restrict__ staged, const int* __restrict__ bbase,
        int* __restrict__ row_ptr, float* __restrict__ dinv,
        int* __restrict__ csr_src, int N, int E) {
    int b = blockIdx.x;
    int t = threadIdx.x;
    int base = bbase[b], end = bbase[b + 1];
    __shared__ int cnt[BNODES];
    __shared__ int cur[BNODES];
    __shared__ int wsum2[2];
    if (t < BNODES) cnt[t] = 0;
    __syncthreads();
    for (int i = base + t; i < end; i += 256)
        atomicAdd(&cnt[staged[i] >> 25], 1);
    __syncthreads();

    // exclusive scan of cnt[0..127] using waves 0,1
    bool act = t < BNODES;
    int v = act ? cnt[t] : 0;
    int lane = t & 63, wv = t >> 6;
    int x = v;
    #pragma unroll
    for (int o = 1; o < 64; o <<= 1) {
        int y = __shfl_up(x, o);
        if (lane >= o) x += y;
    }
    if (lane == 63 && wv == 0) wsum2[0] = x;
    __syncthreads();
    if (act) {
        int excl = x - v + (wv == 1 ? wsum2[0] : 0);
        int gnode = b * BNODES + t;
        int rp = base + excl;
        cur[t] = rp;
        if (gnode < N) {
            row_ptr[gnode] = rp;
            dinv[gnode] = rsqrtf((float)v + 1.0f);
        }
    }
    __syncthreads();
    for (int i = base + t; i < end; i += 256) {
        unsigned int u = staged[i];
        int dl = u >> 25;
        int p = atomicAdd(&cur[dl], 1);
        csr_src[p] = (int)(u & 0x1FFFFFFu);
    }
    if (b == 0 && t == 0) row_ptr[N] = E;
}

// ---- weight convert: W[k][n] fp32 -> Wt[n][k] bf16 ----
__global__ __launch_bounds__(256) void convw_kernel(
        const float* __restrict__ W, __hip_bfloat16* __restrict__ Wt, int K, int Ncol) {
    int idx = blockIdx.x * 256 + threadIdx.x;
    if (idx < K * Ncol) {
        int n = idx / K, k = idx - n * K;
        ((unsigned short*)Wt)[idx] = bf16_rn(W[k * Ncol + n]);
    }
}

// ---- MFMA GEMM: Y[N][128] = X[N][128] @ W, Wt[n][k] bf16 ----
template <bool IN_FP32>
__global__ __launch_bounds__(256) void mfma_gemm_kernel(
        const void* __restrict__ Xv, const __hip_bfloat16* __restrict__ Wt,
        __hip_bfloat16* __restrict__ Y, int N) {
    __shared__ short Ws[FEAT][136];
    int t = threadIdx.x;
    for (int i = t; i < FEAT * 16; i += 256) {
        int n = i >> 4, c = i & 15;
        *(uint4*)&Ws[n][c * 8] = *(const uint4*)((const unsigned short*)Wt + n * FEAT + c * 8);
    }
    __syncthreads();

    int wave = t >> 6, lane = t & 63;
    int m = lane & 15, quad = lane >> 4;
    int rbase = (blockIdx.x * 4 + wave) * 16;
    if (rbase >= N) return;                 // wave-uniform
    int row = rbase + m;
    bool rok = row < N;

    f32x4 acc[8];
    #pragma unroll
    for (int nt = 0; nt < 8; ++nt) acc[nt] = (f32x4){0.f, 0.f, 0.f, 0.f};

    #pragma unroll
    for (int ks = 0; ks < 4; ++ks) {
        short8 a;
        if (IN_FP32) {
            const float* X = (const float*)Xv;
            float xs[8];
            if (rok) {
                float4 x0 = *(const float4*)(X + (size_t)row * FEAT + ks * 32 + quad * 8);
                float4 x1 = *(const float4*)(X + (size_t)row * FEAT + ks * 32 + quad * 8 + 4);
                xs[0] = x0.x; xs[1] = x0.y; xs[2] = x0.z; xs[3] = x0.w;
                xs[4] = x1.x; xs[5] = x1.y; xs[6] = x1.z; xs[7] = x1.w;
            } else {
                #pragma unroll
                for (int j = 0; j < 8; ++j) xs[j] = 0.f;
            }
            #pragma unroll
            for (int j = 0; j < 8; ++j) a[j] = (short)bf16_rn(xs[j]);
        } else {
            const unsigned short* X = (const unsigned short*)Xv;
            if (rok)
                a = *(const short8*)(X + (size_t)row * FEAT + ks * 32 + quad * 8);
            else {
                #pragma unroll
                for (int j = 0; j < 8; ++j) a[j] = 0;
            }
        }
        #pragma unroll
        for (int nt = 0; nt < 8; ++nt) {
            short8 bfr = *(const short8*)&Ws[nt * 16 + m][ks * 32 + quad * 8];
            acc[nt] = __builtin_amdgcn_mfma_f32_16x16x32_bf16(a, bfr, acc[nt], 0, 0, 0);
        }
    }

    unsigned short* Yo = (unsigned short*)Y;
    #pragma unroll
    for (int nt = 0; nt < 8; ++nt) {
        #pragma unroll
        for (int r = 0; r < 4; ++r) {
            int ro = rbase + quad * 4 + r;
            if (ro < N)
                Yo[(size_t)ro * FEAT + nt * 16 + m] = bf16_rn(acc[nt][r]);
        }
    }
}

// ---- CSR gather (bf16 H): A[d] = relu(sum H[s]*w + H[d]*di^2 + b) ----
__global__ __launch_bounds__(256) void gather_kernel(
        const int* __restrict__ row_ptr, const int* __restrict__ csr_src,
        const float* __restrict__ dinv, const __hip_bfloat16* __restrict__ H,
        const float* __restrict__ bias, __hip_bfloat16* __restrict__ A, int N) {
    int node = blockIdx.x * 4 + (threadIdx.x >> 6);
    if (node >= N) return;
    int lane = threadIdx.x & 63;
    const unsigned int* H2 = (const unsigned int*)H;
    float di = dinv[node];
    float2 b2 = ((const float2*)bias)[lane];
    unsigned int hu = H2[(size_t)node * 64 + lane];
    float ax = bf16_lo(hu) * di * di + b2.x;
    float ay = bf16_hi(hu) * di * di + b2.y;

    int j = row_ptr[node], end = row_ptr[node + 1];
    for (; j + 4 <= end; j += 4) {
        int s0 = csr_src[j + 0], s1 = csr_src[j + 1];
        int s2 = csr_src[j + 2], s3 = csr_src[j + 3];
        float w0 = dinv[s0] * di, w1 = dinv[s1] * di;
        float w2 = dinv[s2] * di, w3 = dinv[s3] * di;
        unsigned int u0 = H2[(size_t)s0 * 64 + lane];
        unsigned int u1 = H2[(size_t)s1 * 64 + lane];
        unsigned int u2 = H2[(size_t)s2 * 64 + lane];
        unsigned int u3 = H2[(size_t)s3 * 64 + lane];
        ax += bf16_lo(u0) * w0 + bf16_lo(u1) * w1 + bf16_lo(u2) * w2 + bf16_lo(u3) * w3;
        ay += bf16_hi(u0) * w0 + bf16_hi(u1) * w1 + bf16_hi(u2) * w2 + bf16_hi(u3) * w3;
    }
    for (; j < end; ++j) {
        int s = csr_src[j];
        float w = dinv[s] * di;
        unsigned int u = H2[(size_t)s * 64 + lane];
        ax += bf16_lo(u) * w;
        ay += bf16_hi(u) * w;
    }
    ax = fmaxf(ax, 0.f); ay = fmaxf(ay, 0.f);
    unsigned int packed = (unsigned int)bf16_rn(ax) | ((unsigned int)bf16_rn(ay) << 16);
    ((unsigned int*)A)[(size_t)node * 64 + lane] = packed;
}

// ---- final: logits = H@Wout + bout ; log_softmax across 64 lanes ----
__global__ __launch_bounds__(256) void final_kernel(
        const __hip_bfloat16* __restrict__ H, const float* __restrict__ Wout,
        const float* __restrict__ bout, float* __restrict__ out, int N) {
    __shared__ float Ws[FEAT][OUTF];   // 32 KB
    int t = threadIdx.x;
    for (int i = t; i < FEAT * OUTF; i += 256)
        Ws[i >> 6][i & 63] = Wout[i];
    __syncthreads();

    int wave = t >> 6;
    int lane = t & 63;
    float bj = bout[lane];
    int rbase = blockIdx.x * 16 + wave * 4;

    for (int r = 0; r < 4; ++r) {
        int row = rbase + r;
        if (row >= N) continue;              // wave-uniform
        const uint4* h16 = (const uint4*)((const unsigned short*)H + (size_t)row * FEAT);
        float acc = bj;
        #pragma unroll
        for (int i = 0; i < 8; ++i) {
            uint4 q = h16[i];
            acc += bf16_lo(q.x) * Ws[8 * i + 0][lane] + bf16_hi(q.x) * Ws[8 * i + 1][lane]
                 + bf16_lo(q.y) * Ws[8 * i + 2][lane] + bf16_hi(q.y) * Ws[8 * i + 3][lane]
                 + bf16_lo(q.z) * Ws[8 * i + 4][lane] + bf16_hi(q.z) * Ws[8 * i + 5][lane]
                 + bf16_lo(q.w) * Ws[8 * i + 6][lane] + bf16_hi(q.w) * Ws[8 * i + 7][lane];
        }
        float mx = acc;
        #pragma unroll
        for (int o = 32; o > 0; o >>= 1) mx = fmaxf(mx, __shfl_xor(mx, o));
        float ev = __expf(acc - mx);
        float s = ev;
        #pragma unroll
        for (int o = 32; o > 0; o >>= 1) s += __shfl_xor(s, o);
        out[(size_t)row * OUTF + lane] = acc - mx - __logf(s);
    }
}

extern "C" void kernel_launch(void* const* d_in, const int* in_sizes, int n_in,
                              void* d_out, int out_size, void* d_ws, size_t ws_size,
                              hipStream_t stream) {
    const float* x    = (const float*)d_in[0];
    const int*   ei   = (const int*)  d_in[1];
    const float* W1   = (const float*)d_in[2];
    const float* b1   = (const float*)d_in[3];
    const float* W2   = (const float*)d_in[4];
    const float* b2   = (const float*)d_in[5];
    const float* Wout = (const float*)d_in[6];
    const float* bout = (const float*)d_in[7];
    float* out = (float*)d_out;

    int N = in_sizes[0] / FEAT;
    int E = in_sizes[1] / 2;
    const int* srcp = ei;
    const int* dstp = ei + E;
    int NB = (N + BNODES - 1) >> BSH;   // <= 1024 for N <= 131072

    char* ws = (char*)d_ws;
    __hip_bfloat16* Bh  = (__hip_bfloat16*)ws;                    // N*128 bf16
    __hip_bfloat16* Ba  = Bh + (size_t)N * FEAT;                  // N*128 bf16
    __hip_bfloat16* W1t = Ba + (size_t)N * FEAT;                  // 128*128 bf16
    __hip_bfloat16* W2t = W1t + FEAT * FEAT;                      // 128*128 bf16
    float* dinv    = (float*)(W2t + FEAT * FEAT);                 // N
    int*   rowp    = (int*)(dinv + N);                            // N+1
    int*   bcnt    = rowp + N + 1;                                // NB
    int*   bbase   = bcnt + 1024;                                 // NB+1
    int*   bcur    = bbase + 1025;                                // NB
    unsigned int* staged = (unsigned int*)(bcur + 1024);          // E
    int*   csrsrc  = (int*)(staged + E);                          // E

    hipMemsetAsync(bcnt, 0, (size_t)NB * sizeof(int), stream);
    bincount_kernel<<<256, 256, 0, stream>>>(dstp, bcnt, E, NB);
    bucket_scan_kernel<<<1, 256, 0, stream>>>(bcnt, bbase, bcur, NB, E);
    bin_scatter_kernel<<<(E + 255) / 256, 256, 0, stream>>>(srcp, dstp, bbase, bcur, staged, E);
    bucket_place_kernel<<<NB, 256, 0, stream>>>(staged, bbase, rowp, dinv, csrsrc, N, E);

    convw_kernel<<<(FEAT * FEAT + 255) / 256, 256, 0, stream>>>(W1, W1t, FEAT, FEAT);
    convw_kernel<<<(FEAT * FEAT + 255) / 256, 256, 0, stream>>>(W2, W2t, FEAT, FEAT);

    int ggrid = (N + 63) / 64;

    // Layer 1
    mfma_gemm_kernel<true><<<ggrid, 256, 0, stream>>>(x, W1t, Bh, N);
    gather_kernel<<<(N + 3) / 4, 256, 0, stream>>>(rowp, csrsrc, dinv, Bh, b1, Ba, N);

    // Layer 2
    mfma_gemm_kernel<false><<<ggrid, 256, 0, stream>>>(Ba, W2t, Bh, N);
    gather_kernel<<<(N + 3) / 4, 256, 0, stream>>>(rowp, csrsrc, dinv, Bh, b2, Ba, N);

    // Output layer + log_softmax
    final_kernel<<<(N + 15) / 16, 256, 0, stream>>>(Ba, Wout, bout, out, N);
}

// Round 5
// 403.614 us; speedup vs baseline: 1.8514x; 1.8514x over previous
//
#include <hip/hip_runtime.h>
#include <hip/hip_bf16.h>

// 3-layer GCN. Round 5: bucketed CSR build with two-phase (LDS-aggregated)
// scatter to kill global atomic contention seen in R4.
//   bincount (LDS histogram, 128-node buckets) -> bucket_scan (1 block)
//   -> bin_scatter (per-block LDS histogram + one global reserve per bucket)
//   -> bucket_place (per-bucket LDS scan: row_ptr, dinv, csr_src)
// GEMMs: bf16 MFMA 16x16x32. Aggregation: CSR wave-per-node gather, bf16 H.
// Requires N <= 131072 (bucket count <= 1024) and N < 2^25 for packing.

#define FEAT 128
#define OUTF 64
#define BSH 7                 // 128 nodes per bucket
#define BNODES (1 << BSH)
#define SCHUNK 8192           // edges per bin_scatter block

typedef __attribute__((ext_vector_type(8))) short short8;
typedef __attribute__((ext_vector_type(4))) float f32x4;

__device__ __forceinline__ unsigned short bf16_rn(float f) {
    unsigned int u = __float_as_uint(f);
    u += 0x7FFFu + ((u >> 16) & 1u);   // round-to-nearest-even
    return (unsigned short)(u >> 16);
}
__device__ __forceinline__ float bf16_lo(unsigned int u) { return __uint_as_float(u << 16); }
__device__ __forceinline__ float bf16_hi(unsigned int u) { return __uint_as_float(u & 0xFFFF0000u); }

// ---- k1: per-bucket edge counts (LDS histogram; NB <= 1024) ----
__global__ __launch_bounds__(256) void bincount_kernel(
        const int* __restrict__ dst, int* __restrict__ bcnt, int E, int NB) {
    __shared__ int h[1024];
    int t = threadIdx.x;
    for (int i = t; i < NB; i += 256) h[i] = 0;
    __syncthreads();
    int stride = gridDim.x * 256;
    for (int e = blockIdx.x * 256 + t; e < E; e += stride)
        atomicAdd(&h[dst[e] >> BSH], 1);
    __syncthreads();
    for (int i = t; i < NB; i += 256)
        if (h[i]) atomicAdd(&bcnt[i], h[i]);
}

// ---- k2: exclusive scan of bcnt[NB] -> bbase[NB+1]; zero bcur ----
__global__ __launch_bounds__(256) void bucket_scan_kernel(
        const int* __restrict__ bcnt, int* __restrict__ bbase,
        int* __restrict__ bcur, int NB, int E) {
    int t = threadIdx.x;
    int base = t * 4;
    int v[4];
    #pragma unroll
    for (int i = 0; i < 4; ++i) v[i] = (base + i < NB) ? bcnt[base + i] : 0;
    int local = v[0] + v[1] + v[2] + v[3];
    int lane = t & 63, wv = t >> 6;
    int x = local;
    #pragma unroll
    for (int o = 1; o < 64; o <<= 1) {
        int y = __shfl_up(x, o);
        if (lane >= o) x += y;
    }
    __shared__ int wsum[4];
    if (lane == 63) wsum[wv] = x;
    __syncthreads();
    int woff = 0;
    for (int i = 0; i < wv; ++i) woff += wsum[i];
    int run = woff + x - local;
    #pragma unroll
    for (int i = 0; i < 4; ++i) {
        if (base + i < NB) bbase[base + i] = run;
        run += v[i];
    }
    for (int i = t; i < NB; i += 256) bcur[i] = 0;
    if (t == 0) bbase[NB] = E;
}

// ---- k3: two-phase scatter of packed (src | dlocal<<25), bucket-major ----
// Pass A: LDS histogram of this block's chunk. Reserve: ONE global atomic per
// (block,bucket). Pass B: place via LDS cursors. ~20x less global-atomic
// contention than per-edge reserve, and writes land in ~10-word runs.
__global__ __launch_bounds__(256) void bin_scatter_kernel(
        const int* __restrict__ src, const int* __restrict__ dst,
        const int* __restrict__ bbase, int* __restrict__ bcur,
        unsigned int* __restrict__ staged, int E, int NB) {
    __shared__ int lcnt[1024];
    __shared__ int lbase[1024];
    int t = threadIdx.x;
    int e0 = blockIdx.x * SCHUNK;
    int e1 = min(e0 + SCHUNK, E);
    for (int i = t; i < NB; i += 256) lcnt[i] = 0;
    __syncthreads();
    for (int e = e0 + t; e < e1; e += 256)
        atomicAdd(&lcnt[dst[e] >> BSH], 1);
    __syncthreads();
    for (int i = t; i < NB; i += 256) {
        int c = lcnt[i];
        lbase[i] = c ? atomicAdd(&bcur[i], c) : 0;
        lcnt[i] = 0;
    }
    __syncthreads();
    for (int e = e0 + t; e < e1; e += 256) {
        int s = src[e], d = dst[e];
        int b = d >> BSH, dl = d & (BNODES - 1);
        int pos = bbase[b] + lbase[b] + atomicAdd(&lcnt[b], 1);
        staged[pos] = (unsigned int)s | ((unsigned int)dl << 25);
    }
}

// ---- k4: per-bucket finalize: row_ptr, dinv, csr_src ----
__global__ __launch_bounds__(256) void bucket_place_kernel(
        const unsigned int* __restrict__ staged, const int* __restrict__ bbase,
        int* __restrict__ row_ptr, float* __restrict__ dinv,
        int* __restrict__ csr_src, int N, int E) {
    int b = blockIdx.x;
    int t = threadIdx.x;
    int base = bbase[b], end = bbase[b + 1];
    __shared__ int cnt[BNODES];
    __shared__ int cur[BNODES];
    __shared__ int wsum2[2];
    if (t < BNODES) cnt[t] = 0;
    __syncthreads();
    for (int i = base + t; i < end; i += 256)
        atomicAdd(&cnt[staged[i] >> 25], 1);
    __syncthreads();

    // exclusive scan of cnt[0..127] using waves 0,1
    bool act = t < BNODES;
    int v = act ? cnt[t] : 0;
    int lane = t & 63, wv = t >> 6;
    int x = v;
    #pragma unroll
    for (int o = 1; o < 64; o <<= 1) {
        int y = __shfl_up(x, o);
        if (lane >= o) x += y;
    }
    if (lane == 63 && wv == 0) wsum2[0] = x;
    __syncthreads();
    if (act) {
        int excl = x - v + (wv == 1 ? wsum2[0] : 0);
        int gnode = b * BNODES + t;
        int rp = base + excl;
        cur[t] = rp;
        if (gnode < N) {
            row_ptr[gnode] = rp;
            dinv[gnode] = rsqrtf((float)v + 1.0f);
        }
    }
    __syncthreads();
    for (int i = base + t; i < end; i += 256) {
        unsigned int u = staged[i];
        int dl = u >> 25;
        int p = atomicAdd(&cur[dl], 1);
        csr_src[p] = (int)(u & 0x1FFFFFFu);
    }
    if (b == 0 && t == 0) row_ptr[N] = E;
}

// ---- weight convert: W[k][n] fp32 -> Wt[n][k] bf16 ----
__global__ __launch_bounds__(256) void convw_kernel(
        const float* __restrict__ W, __hip_bfloat16* __restrict__ Wt, int K, int Ncol) {
    int idx = blockIdx.x * 256 + threadIdx.x;
    if (idx < K * Ncol) {
        int n = idx / K, k = idx - n * K;
        ((unsigned short*)Wt)[idx] = bf16_rn(W[k * Ncol + n]);
    }
}

// ---- MFMA GEMM: Y[N][128] = X[N][128] @ W, Wt[n][k] bf16 ----
template <bool IN_FP32>
__global__ __launch_bounds__(256) void mfma_gemm_kernel(
        const void* __restrict__ Xv, const __hip_bfloat16* __restrict__ Wt,
        __hip_bfloat16* __restrict__ Y, int N) {
    __shared__ short Ws[FEAT][136];
    int t = threadIdx.x;
    for (int i = t; i < FEAT * 16; i += 256) {
        int n = i >> 4, c = i & 15;
        *(uint4*)&Ws[n][c * 8] = *(const uint4*)((const unsigned short*)Wt + n * FEAT + c * 8);
    }
    __syncthreads();

    int wave = t >> 6, lane = t & 63;
    int m = lane & 15, quad = lane >> 4;
    int rbase = (blockIdx.x * 4 + wave) * 16;
    if (rbase >= N) return;                 // wave-uniform
    int row = rbase + m;
    bool rok = row < N;

    f32x4 acc[8];
    #pragma unroll
    for (int nt = 0; nt < 8; ++nt) acc[nt] = (f32x4){0.f, 0.f, 0.f, 0.f};

    #pragma unroll
    for (int ks = 0; ks < 4; ++ks) {
        short8 a;
        if (IN_FP32) {
            const float* X = (const float*)Xv;
            float xs[8];
            if (rok) {
                float4 x0 = *(const float4*)(X + (size_t)row * FEAT + ks * 32 + quad * 8);
                float4 x1 = *(const float4*)(X + (size_t)row * FEAT + ks * 32 + quad * 8 + 4);
                xs[0] = x0.x; xs[1] = x0.y; xs[2] = x0.z; xs[3] = x0.w;
                xs[4] = x1.x; xs[5] = x1.y; xs[6] = x1.z; xs[7] = x1.w;
            } else {
                #pragma unroll
                for (int j = 0; j < 8; ++j) xs[j] = 0.f;
            }
            #pragma unroll
            for (int j = 0; j < 8; ++j) a[j] = (short)bf16_rn(xs[j]);
        } else {
            const unsigned short* X = (const unsigned short*)Xv;
            if (rok)
                a = *(const short8*)(X + (size_t)row * FEAT + ks * 32 + quad * 8);
            else {
                #pragma unroll
                for (int j = 0; j < 8; ++j) a[j] = 0;
            }
        }
        #pragma unroll
        for (int nt = 0; nt < 8; ++nt) {
            short8 bfr = *(const short8*)&Ws[nt * 16 + m][ks * 32 + quad * 8];
            acc[nt] = __builtin_amdgcn_mfma_f32_16x16x32_bf16(a, bfr, acc[nt], 0, 0, 0);
        }
    }

    unsigned short* Yo = (unsigned short*)Y;
    #pragma unroll
    for (int nt = 0; nt < 8; ++nt) {
        #pragma unroll
        for (int r = 0; r < 4; ++r) {
            int ro = rbase + quad * 4 + r;
            if (ro < N)
                Yo[(size_t)ro * FEAT + nt * 16 + m] = bf16_rn(acc[nt][r]);
        }
    }
}

// ---- CSR gather (bf16 H): A[d] = relu(sum H[s]*w + H[d]*di^2 + b) ----
__global__ __launch_bounds__(256) void gather_kernel(
        const int* __restrict__ row_ptr, const int* __restrict__ csr_src,
        const float* __restrict__ dinv, const __hip_bfloat16* __restrict__ H,
        const float* __restrict__ bias, __hip_bfloat16* __restrict__ A, int N) {
    int node = blockIdx.x * 4 + (threadIdx.x >> 6);
    if (node >= N) return;
    int lane = threadIdx.x & 63;
    const unsigned int* H2 = (const unsigned int*)H;
    float di = dinv[node];
    float2 b2 = ((const float2*)bias)[lane];
    unsigned int hu = H2[(size_t)node * 64 + lane];
    float ax = bf16_lo(hu) * di * di + b2.x;
    float ay = bf16_hi(hu) * di * di + b2.y;

    int j = row_ptr[node], end = row_ptr[node + 1];
    for (; j + 4 <= end; j += 4) {
        int s0 = csr_src[j + 0], s1 = csr_src[j + 1];
        int s2 = csr_src[j + 2], s3 = csr_src[j + 3];
        float w0 = dinv[s0] * di, w1 = dinv[s1] * di;
        float w2 = dinv[s2] * di, w3 = dinv[s3] * di;
        unsigned int u0 = H2[(size_t)s0 * 64 + lane];
        unsigned int u1 = H2[(size_t)s1 * 64 + lane];
        unsigned int u2 = H2[(size_t)s2 * 64 + lane];
        unsigned int u3 = H2[(size_t)s3 * 64 + lane];
        ax += bf16_lo(u0) * w0 + bf16_lo(u1) * w1 + bf16_lo(u2) * w2 + bf16_lo(u3) * w3;
        ay += bf16_hi(u0) * w0 + bf16_hi(u1) * w1 + bf16_hi(u2) * w2 + bf16_hi(u3) * w3;
    }
    for (; j < end; ++j) {
        int s = csr_src[j];
        float w = dinv[s] * di;
        unsigned int u = H2[(size_t)s * 64 + lane];
        ax += bf16_lo(u) * w;
        ay += bf16_hi(u) * w;
    }
    ax = fmaxf(ax, 0.f); ay = fmaxf(ay, 0.f);
    unsigned int packed = (unsigned int)bf16_rn(ax) | ((unsigned int)bf16_rn(ay) << 16);
    ((unsigned int*)A)[(size_t)node * 64 + lane] = packed;
}

// ---- final: logits = H@Wout + bout ; log_softmax across 64 lanes ----
__global__ __launch_bounds__(256) void final_kernel(
        const __hip_bfloat16* __restrict__ H, const float* __restrict__ Wout,
        const float* __restrict__ bout, float* __restrict__ out, int N) {
    __shared__ float Ws[FEAT][OUTF];   // 32 KB
    int t = threadIdx.x;
    for (int i = t; i < FEAT * OUTF; i += 256)
        Ws[i >> 6][i & 63] = Wout[i];
    __syncthreads();

    int wave = t >> 6;
    int lane = t & 63;
    float bj = bout[lane];
    int rbase = blockIdx.x * 16 + wave * 4;

    for (int r = 0; r < 4; ++r) {
        int row = rbase + r;
        if (row >= N) continue;              // wave-uniform
        const uint4* h16 = (const uint4*)((const unsigned short*)H + (size_t)row * FEAT);
        float acc = bj;
        #pragma unroll
        for (int i = 0; i < 8; ++i) {
            uint4 q = h16[i];
            acc += bf16_lo(q.x) * Ws[8 * i + 0][lane] + bf16_hi(q.x) * Ws[8 * i + 1][lane]
                 + bf16_lo(q.y) * Ws[8 * i + 2][lane] + bf16_hi(q.y) * Ws[8 * i + 3][lane]
                 + bf16_lo(q.z) * Ws[8 * i + 4][lane] + bf16_hi(q.z) * Ws[8 * i + 5][lane]
                 + bf16_lo(q.w) * Ws[8 * i + 6][lane] + bf16_hi(q.w) * Ws[8 * i + 7][lane];
        }
        float mx = acc;
        #pragma unroll
        for (int o = 32; o > 0; o >>= 1) mx = fmaxf(mx, __shfl_xor(mx, o));
        float ev = __expf(acc - mx);
        float s = ev;
        #pragma unroll
        for (int o = 32; o > 0; o >>= 1) s += __shfl_xor(s, o);
        out[(size_t)row * OUTF + lane] = acc - mx - __logf(s);
    }
}

extern "C" void kernel_launch(void* const* d_in, const int* in_sizes, int n_in,
                              void* d_out, int out_size, void* d_ws, size_t ws_size,
                              hipStream_t stream) {
    const float* x    = (const float*)d_in[0];
    const int*   ei   = (const int*)  d_in[1];
    const float* W1   = (const float*)d_in[2];
    const float* b1   = (const float*)d_in[3];
    const float* W2   = (const float*)d_in[4];
    const float* b2   = (const float*)d_in[5];
    const float* Wout = (const float*)d_in[6];
    const float* bout = (const float*)d_in[7];
    float* out = (float*)d_out;

    int N = in_sizes[0] / FEAT;
    int E = in_sizes[1] / 2;
    const int* srcp = ei;
    const int* dstp = ei + E;
    int NB = (N + BNODES - 1) >> BSH;   // <= 1024 for N <= 131072

    char* ws = (char*)d_ws;
    __hip_bfloat16* Bh  = (__hip_bfloat16*)ws;                    // N*128 bf16
    __hip_bfloat16* Ba  = Bh + (size_t)N * FEAT;                  // N*128 bf16
    __hip_bfloat16* W1t = Ba + (size_t)N * FEAT;                  // 128*128 bf16
    __hip_bfloat16* W2t = W1t + FEAT * FEAT;                      // 128*128 bf16
    float* dinv    = (float*)(W2t + FEAT * FEAT);                 // N
    int*   rowp    = (int*)(dinv + N);                            // N+1
    int*   bcnt    = rowp + N + 1;                                // NB
    int*   bbase   = bcnt + 1024;                                 // NB+1
    int*   bcur    = bbase + 1025;                                // NB
    unsigned int* staged = (unsigned int*)(bcur + 1024);          // E
    int*   csrsrc  = (int*)(staged + E);                          // E

    hipMemsetAsync(bcnt, 0, (size_t)NB * sizeof(int), stream);
    bincount_kernel<<<256, 256, 0, stream>>>(dstp, bcnt, E, NB);
    bucket_scan_kernel<<<1, 256, 0, stream>>>(bcnt, bbase, bcur, NB, E);
    bin_scatter_kernel<<<(E + SCHUNK - 1) / SCHUNK, 256, 0, stream>>>(
        srcp, dstp, bbase, bcur, staged, E, NB);
    bucket_place_kernel<<<NB, 256, 0, stream>>>(staged, bbase, rowp, dinv, csrsrc, N, E);

    convw_kernel<<<(FEAT * FEAT + 255) / 256, 256, 0, stream>>>(W1, W1t, FEAT, FEAT);
    convw_kernel<<<(FEAT * FEAT + 255) / 256, 256, 0, stream>>>(W2, W2t, FEAT, FEAT);

    int ggrid = (N + 63) / 64;

    // Layer 1
    mfma_gemm_kernel<true><<<ggrid, 256, 0, stream>>>(x, W1t, Bh, N);
    gather_kernel<<<(N + 3) / 4, 256, 0, stream>>>(rowp, csrsrc, dinv, Bh, b1, Ba, N);

    // Layer 2
    mfma_gemm_kernel<false><<<ggrid, 256, 0, stream>>>(Ba, W2t, Bh, N);
    gather_kernel<<<(N + 3) / 4, 256, 0, stream>>>(rowp, csrsrc, dinv, Bh, b2, Ba, N);

    // Output layer + log_softmax
    final_kernel<<<(N + 15) / 16, 256, 0, stream>>>(Ba, Wout, bout, out, N);
}